// Round 8
// baseline (764.265 us; speedup 1.0000x reference)
//
#include <hip/hip_runtime.h>
#include <hip/hip_bf16.h>
#include <math.h>

#define N_ATOMS 8192
#define N_EDGES 262144
#define N_MOL   128
#define FDIM    128
#define RDIM    20
#define LLAYERS 3
#define CUTOFF  5.0f
#define EPSV    1e-8f
#define PI_F    3.14159265358979323846f

typedef __attribute__((ext_vector_type(8))) short bf16x8;
typedef __attribute__((ext_vector_type(4))) float f32x4;
typedef __attribute__((ext_vector_type(2))) float f32x2;

#define VPLANE 1048576   // 8192*128 elements per component plane

__device__ __forceinline__ ushort f2bf(float x) {
    uint b = __float_as_uint(x);
    return (ushort)((b + 0x7fffu + ((b >> 16) & 1u)) >> 16);
}

// ---------------- weight convert+transpose (f32 KxN -> bf16 NxK) ----------------
__global__ void k_wconv(const float* __restrict__ w1, const float* __restrict__ w2,
                        const float* __restrict__ uu, const float* __restrict__ uvw,
                        const float* __restrict__ a1, const float* __restrict__ a2,
                        const float* __restrict__ ow1, ushort* __restrict__ WT) {
    int i = blockIdx.x * 256 + threadIdx.x;  // < 557056
    float v;
    if (i < 49152) {                          // W1T
        int idx = i; int l = idx >> 14; idx &= 16383;
        int n = idx >> 7, k = idx & 127;
        v = w1[l*16384 + k*128 + n];
    } else if (i < 196608) {                  // W2T
        int idx = i - 49152; int l = idx / 49152; idx -= l * 49152;
        int n = idx >> 7, k = idx & 127;
        v = w2[l*49152 + k*384 + n];
    } else if (i < 294912) {                  // UVT (u cols 0-127, v cols 128-255)
        int idx = i - 196608; int l = idx >> 15; idx &= 32767;
        int n = idx >> 7, k = idx & 127;
        v = (n < 128) ? uu[l*16384 + k*128 + n] : uvw[l*16384 + k*128 + (n-128)];
    } else if (i < 393216) {                  // A1T (128n x 256k)
        int idx = i - 294912; int l = idx >> 15; idx &= 32767;
        int n = idx >> 8, k = idx & 255;
        v = a1[l*32768 + k*128 + n];
    } else if (i < 540672) {                  // A2T
        int idx = i - 393216; int l = idx / 49152; idx -= l * 49152;
        int n = idx >> 7, k = idx & 127;
        v = a2[l*49152 + k*384 + n];
    } else {                                  // OW1T
        int idx = i - 540672;
        int n = idx >> 7, k = idx & 127;
        v = ow1[k*128 + n];
    }
    WT[i] = f2bf(v);
}

// ---------------- embed gather ----------------
__global__ void k_embed(const int* __restrict__ z, const float* __restrict__ embed,
                        float* __restrict__ S, ushort* __restrict__ SBF) {
    int i = blockIdx.x * 256 + threadIdx.x;
    int a = i >> 7, k = i & 127;
    float v = embed[(size_t)z[a] * FDIM + k];
    S[i] = v; SBF[i] = f2bf(v);
}

// ---------------- CSR build ----------------
__global__ void k_hist(const int* __restrict__ edst, int* __restrict__ CNT) {
    int e = blockIdx.x * 256 + threadIdx.x;
    if (e < N_EDGES) atomicAdd(&CNT[edst[e]], 1);
}

__global__ __launch_bounds__(1024) void k_scan(const int* __restrict__ CNT,
                                               int* __restrict__ OFF, int* __restrict__ CUR) {
    __shared__ int part[1024];
    int t = threadIdx.x;
    int loc[8];
    int run = 0;
    #pragma unroll
    for (int i = 0; i < 8; i++) { int c = CNT[t*8 + i]; loc[i] = run; run += c; }
    part[t] = run;
    __syncthreads();
    for (int off = 1; off < 1024; off <<= 1) {
        int v = 0;
        if (t >= off) v = part[t - off];
        __syncthreads();
        part[t] += v;
        __syncthreads();
    }
    int ebase = (t > 0) ? part[t-1] : 0;
    #pragma unroll
    for (int i = 0; i < 8; i++) { int o = ebase + loc[i]; OFF[t*8+i] = o; CUR[t*8+i] = o; }
    if (t == 1023) OFF[8192] = part[1023];
}

__global__ void k_pos(const int* __restrict__ edst, int* __restrict__ CUR,
                      int* __restrict__ POS) {
    int e = blockIdx.x * 256 + threadIdx.x;
    if (e < N_EDGES) POS[e] = atomicAdd(&CUR[edst[e]], 1);
}

// ---------------- edge geometry + rbf, CSR-sorted ----------------
__global__ void k_edges(const float* __restrict__ pos, const int* __restrict__ esrc,
                        const int* __restrict__ edst, const int* __restrict__ POS,
                        float* __restrict__ RBF, float* __restrict__ UNITFC,
                        int* __restrict__ SRCS) {
    int e = blockIdx.x * 256 + threadIdx.x;
    if (e >= N_EDGES) return;
    int s = esrc[e], d = edst[e];
    int p = POS[e];
    float rx = pos[d*3+0] - pos[s*3+0];
    float ry = pos[d*3+1] - pos[s*3+1];
    float rz = pos[d*3+2] - pos[s*3+2];
    float dd = sqrtf(rx*rx + ry*ry + rz*rz + EPSV);
    float inv = 1.0f / dd;
    float fc = (dd < CUTOFF) ? 0.5f * (cosf(dd * (PI_F / CUTOFF)) + 1.0f) : 0.0f;
    float4 u4; u4.x = rx*inv; u4.y = ry*inv; u4.z = rz*inv; u4.w = fc;
    *(float4*)&UNITFC[(size_t)p*4] = u4;
    SRCS[p] = s;
    float rb[RDIM];
    #pragma unroll
    for (int r = 0; r < RDIM; r++) {
        float freq = (float)(r + 1) * (PI_F / CUTOFF);
        rb[r] = sinf(dd * freq) * inv;
    }
    float4* out = (float4*)&RBF[(size_t)p * RDIM];
    #pragma unroll
    for (int q = 0; q < 5; q++) {
        float4 o; o.x = rb[q*4]; o.y = rb[q*4+1]; o.z = rb[q*4+2]; o.w = rb[q*4+3];
        out[q] = o;
    }
}

// ---------------- fused message MLP: PHIB = (silu(S@w1+b1))@w2+b2 ----------------
__global__ __launch_bounds__(64) void k_msg(
    const ushort* __restrict__ SBF, const ushort* __restrict__ W1T, const float* __restrict__ b1,
    const ushort* __restrict__ W2T, const float* __restrict__ b2, ushort* __restrict__ PHIB)
{
    int l = threadIdx.x;
    int bm = blockIdx.x * 16;
    int lrow = l & 15, lk = (l >> 4) * 8;
    __shared__ ushort Hs[16][136];

    f32x4 acc[8];
    #pragma unroll
    for (int t = 0; t < 8; t++) acc[t] = (f32x4){0.f,0.f,0.f,0.f};
    #pragma unroll
    for (int k0 = 0; k0 < 128; k0 += 32) {
        bf16x8 af = *(const bf16x8*)&SBF[(size_t)(bm + lrow)*128 + k0 + lk];
        #pragma unroll
        for (int t = 0; t < 8; t++) {
            bf16x8 bf = *(const bf16x8*)&W1T[(size_t)(t*16 + lrow)*128 + k0 + lk];
            acc[t] = __builtin_amdgcn_mfma_f32_16x16x32_bf16(af, bf, acc[t], 0, 0, 0);
        }
    }
    #pragma unroll
    for (int t = 0; t < 8; t++) {
        int col = t*16 + lrow;
        float bv = b1[col];
        #pragma unroll
        for (int j = 0; j < 4; j++) {
            int row = (l >> 4)*4 + j;
            float val = acc[t][j] + bv;
            val = val / (1.0f + __expf(-val));
            Hs[row][col] = f2bf(val);
        }
    }
    __syncthreads();

    f32x4 acc2[24];
    #pragma unroll
    for (int t = 0; t < 24; t++) acc2[t] = (f32x4){0.f,0.f,0.f,0.f};
    #pragma unroll
    for (int k0 = 0; k0 < 128; k0 += 32) {
        bf16x8 af = *(const bf16x8*)&Hs[lrow][k0 + lk];
        #pragma unroll
        for (int t = 0; t < 24; t++) {
            bf16x8 bf = *(const bf16x8*)&W2T[(size_t)(t*16 + lrow)*128 + k0 + lk];
            acc2[t] = __builtin_amdgcn_mfma_f32_16x16x32_bf16(af, bf, acc2[t], 0, 0, 0);
        }
    }
    #pragma unroll
    for (int t = 0; t < 24; t++) {
        int col = t*16 + lrow;
        float bv = b2[col];
        #pragma unroll
        for (int j = 0; j < 4; j++) {
            int row = bm + (l >> 4)*4 + j;
            PHIB[(size_t)row*384 + col] = f2bf(acc2[t][j] + bv);
        }
    }
}

// ---------------- edge aggregation v6: pk-f32 filter + group-of-4 pipeline ----------------
__global__ __launch_bounds__(192) void k_aggregate(
    const ushort* __restrict__ PHIB, const ushort* __restrict__ VBFA,
    float* __restrict__ S, ushort* __restrict__ SBF,
    float* __restrict__ V, ushort* __restrict__ VBFB,
    const float* __restrict__ RBF, const float* __restrict__ UNITFC,
    const int* __restrict__ SRCS, const int* __restrict__ OFF,
    const float* __restrict__ rbfw, const float* __restrict__ rbfb)
{
    int a = blockIdx.x;
    int tid = threadIdx.x;
    int g = tid >> 6;          // wave role: 0=ds, 1=v*dvv, 2=unit*dvs
    int c0 = 2 * (tid & 63);   // channel pair within section

    f32x2 w[RDIM];
    const float* wc = rbfw + g*128 + c0;
    #pragma unroll
    for (int r = 0; r < RDIM; r++) { w[r] = (f32x2){wc[r*384], wc[r*384 + 1]}; }
    f32x2 bb = (f32x2){rbfb[g*128 + c0], rbfb[g*128 + c0 + 1]};

    __shared__ int sSrc[64];
    __shared__ float4 sRBF[320];
    __shared__ float4 sUFC[64];
    __shared__ float avs[3][128];

    int beg = OFF[a], end = OFF[a + 1];
    f32x2 d = (f32x2){0.f, 0.f};
    f32x2 A0 = d, A1 = d, A2v = d;

    for (int p0 = beg; p0 < end; p0 += 64) {
        int n = end - p0; if (n > 64) n = 64;
        __syncthreads();
        if (tid < n) sSrc[tid] = SRCS[p0 + tid];
        for (int i = tid; i < n; i += 192)
            sUFC[i] = *(const float4*)(UNITFC + (size_t)(p0 + i) * 4);
        {
            const float4* rsrc = (const float4*)(RBF + (size_t)p0 * RDIM);
            for (int i = tid; i < n*5; i += 192) sRBF[i] = rsrc[i];
        }
        __syncthreads();

        uint phA[4], u0A[4], u1A[4], u2A[4];
        uint phB[4], u0B[4], u1B[4], u2B[4];

        auto grpLoad = [&](int base, uint* ph, uint* u0, uint* u1, uint* u2) {
            #pragma unroll
            for (int j = 0; j < 4; j++) {
                int q = base + j;
                int src = sSrc[(q < n) ? q : 0];
                size_t pb = (size_t)src * 128;
                ph[j] = *(const uint*)&PHIB[(size_t)src*384 + g*128 + c0];
                if (g == 1) {
                    u0[j] = *(const uint*)&VBFA[pb + c0];
                    u1[j] = *(const uint*)&VBFA[pb + VPLANE + c0];
                    u2[j] = *(const uint*)&VBFA[pb + 2*VPLANE + c0];
                }
            }
        };
        grpLoad(0, phA, u0A, u1A, u2A);
        for (int q0 = 0; q0 < n; q0 += 4) {
            if (q0 + 4 < n) grpLoad(q0 + 4, phB, u0B, u1B, u2B);
            #pragma unroll
            for (int j = 0; j < 4; j++) {
                int q = q0 + j;
                if (q >= n) break;
                float4 r0 = sRBF[q*5+0], r1 = sRBF[q*5+1], r2 = sRBF[q*5+2],
                       r3 = sRBF[q*5+3], r4 = sRBF[q*5+4];
                float4 ufc = sUFC[q];
                f32x2 f = bb;
                f += (f32x2){r0.x, r0.x} * w[0];
                f += (f32x2){r0.y, r0.y} * w[1];
                f += (f32x2){r0.z, r0.z} * w[2];
                f += (f32x2){r0.w, r0.w} * w[3];
                f += (f32x2){r1.x, r1.x} * w[4];
                f += (f32x2){r1.y, r1.y} * w[5];
                f += (f32x2){r1.z, r1.z} * w[6];
                f += (f32x2){r1.w, r1.w} * w[7];
                f += (f32x2){r2.x, r2.x} * w[8];
                f += (f32x2){r2.y, r2.y} * w[9];
                f += (f32x2){r2.z, r2.z} * w[10];
                f += (f32x2){r2.w, r2.w} * w[11];
                f += (f32x2){r3.x, r3.x} * w[12];
                f += (f32x2){r3.y, r3.y} * w[13];
                f += (f32x2){r3.z, r3.z} * w[14];
                f += (f32x2){r3.w, r3.w} * w[15];
                f += (f32x2){r4.x, r4.x} * w[16];
                f += (f32x2){r4.y, r4.y} * w[17];
                f += (f32x2){r4.z, r4.z} * w[18];
                f += (f32x2){r4.w, r4.w} * w[19];
                uint up = phA[j];
                float m0 = __uint_as_float(up << 16)         * (f.x * ufc.w);
                float m1 = __uint_as_float(up & 0xffff0000u) * (f.y * ufc.w);
                if (g == 0) {
                    d.x += m0; d.y += m1;
                } else if (g == 1) {
                    A0.x  += __uint_as_float(u0A[j] << 16)         * m0;
                    A0.y  += __uint_as_float(u0A[j] & 0xffff0000u) * m1;
                    A1.x  += __uint_as_float(u1A[j] << 16)         * m0;
                    A1.y  += __uint_as_float(u1A[j] & 0xffff0000u) * m1;
                    A2v.x += __uint_as_float(u2A[j] << 16)         * m0;
                    A2v.y += __uint_as_float(u2A[j] & 0xffff0000u) * m1;
                } else {
                    A0.x  += ufc.x * m0; A0.y  += ufc.x * m1;
                    A1.x  += ufc.y * m0; A1.y  += ufc.y * m1;
                    A2v.x += ufc.z * m0; A2v.y += ufc.z * m1;
                }
            }
            #pragma unroll
            for (int j = 0; j < 4; j++) {
                phA[j] = phB[j]; u0A[j] = u0B[j]; u1A[j] = u1B[j]; u2A[j] = u2B[j];
            }
        }
    }

    if (g == 1) {
        avs[0][c0] = A0.x;  avs[0][c0+1] = A0.y;
        avs[1][c0] = A1.x;  avs[1][c0+1] = A1.y;
        avs[2][c0] = A2v.x; avs[2][c0+1] = A2v.y;
    }
    __syncthreads();
    if (g == 0) {
        size_t sb = (size_t)a*128 + c0;
        float2 s2 = *(float2*)&S[sb];
        s2.x += d.x; s2.y += d.y;
        *(float2*)&S[sb] = s2;
        SBF[sb] = f2bf(s2.x); SBF[sb+1] = f2bf(s2.y);
    } else if (g == 2) {
        float own0[3] = {A0.x, A1.x, A2v.x};
        float own1[3] = {A0.y, A1.y, A2v.y};
        #pragma unroll
        for (int c = 0; c < 3; c++) {
            size_t vb = (size_t)c*VPLANE + (size_t)a*128 + c0;
            float2 vi = *(const float2*)&V[vb];
            vi.x += avs[c][c0]     + own0[c];
            vi.y += avs[c][c0 + 1] + own1[c];
            *(float2*)&V[vb] = vi;
            VBFB[vb] = f2bf(vi.x); VBFB[vb+1] = f2bf(vi.y);
        }
    }
}

// ---------------- fused UV|VV GEMM + vvnorm/dot (VV stays in registers) ----------------
__global__ __launch_bounds__(128) void k_uvvv(
    const ushort* __restrict__ VBFB, const ushort* __restrict__ UVT,
    float* __restrict__ UV, ushort* __restrict__ VVNB, float* __restrict__ DOT)
{
    int l = threadIdx.x & 63, w = threadIdx.x >> 6;
    int bm = blockIdx.x * 16;
    int lrow = l & 15, lk = (l >> 4) * 8;

    f32x4 au[3][4], av[3][4];
    #pragma unroll
    for (int c = 0; c < 3; c++)
        #pragma unroll
        for (int t = 0; t < 4; t++) {
            au[c][t] = (f32x4){0.f,0.f,0.f,0.f};
            av[c][t] = (f32x4){0.f,0.f,0.f,0.f};
        }

    #pragma unroll
    for (int k0 = 0; k0 < 128; k0 += 32) {
        bf16x8 af[3];
        #pragma unroll
        for (int c = 0; c < 3; c++)
            af[c] = *(const bf16x8*)&VBFB[(size_t)c*VPLANE + (size_t)(bm + lrow)*128 + k0 + lk];
        #pragma unroll
        for (int t = 0; t < 4; t++) {
            int nu = (4*w + t)*16 + lrow;
            bf16x8 bu = *(const bf16x8*)&UVT[(size_t)nu*128 + k0 + lk];
            bf16x8 bv = *(const bf16x8*)&UVT[(size_t)(nu + 128)*128 + k0 + lk];
            #pragma unroll
            for (int c = 0; c < 3; c++) {
                au[c][t] = __builtin_amdgcn_mfma_f32_16x16x32_bf16(af[c], bu, au[c][t], 0, 0, 0);
                av[c][t] = __builtin_amdgcn_mfma_f32_16x16x32_bf16(af[c], bv, av[c][t], 0, 0, 0);
            }
        }
    }

    #pragma unroll
    for (int t = 0; t < 4; t++) {
        int k = (4*w + t)*16 + lrow;
        #pragma unroll
        for (int j = 0; j < 4; j++) {
            int a = bm + (l >> 4)*4 + j;
            float u0 = au[0][t][j], u1 = au[1][t][j], u2 = au[2][t][j];
            float v0 = av[0][t][j], v1 = av[1][t][j], v2 = av[2][t][j];
            size_t base = (size_t)a*128 + k;
            UV[base]            = u0;
            UV[VPLANE + base]   = u1;
            UV[2*VPLANE + base] = u2;
            VVNB[base] = f2bf(sqrtf(v0*v0 + v1*v1 + v2*v2 + EPSV));
            DOT[base]  = u0*v0 + u1*v1 + u2*v2;
        }
    }
}

// ---------------- fused update MLP: a=silu([S|VVN]@a1+b1)@a2+b2 + s/v update ----------------
__global__ __launch_bounds__(64) void k_updmlp(
    const ushort* __restrict__ SBF_in, const ushort* __restrict__ VVNB,
    const ushort* __restrict__ A1T, const float* __restrict__ a1b,
    const ushort* __restrict__ A2T, const float* __restrict__ a2b,
    const float* __restrict__ DOT, const float* __restrict__ UV,
    float* __restrict__ S, ushort* __restrict__ SBF,
    float* __restrict__ V, ushort* __restrict__ VBFA)
{
    int l = threadIdx.x;
    int bm = blockIdx.x * 16;
    int lrow = l & 15, lk = (l >> 4) * 8;
    __shared__ ushort Hs[16][136];

    f32x4 acc[8];
    #pragma unroll
    for (int t = 0; t < 8; t++) acc[t] = (f32x4){0.f,0.f,0.f,0.f};
    #pragma unroll
    for (int k0 = 0; k0 < 256; k0 += 32) {
        int ka = k0 + lk;
        bf16x8 af = (ka < 128)
            ? *(const bf16x8*)&SBF_in[(size_t)(bm + lrow)*128 + ka]
            : *(const bf16x8*)&VVNB[(size_t)(bm + lrow)*128 + ka - 128];
        #pragma unroll
        for (int t = 0; t < 8; t++) {
            bf16x8 bf = *(const bf16x8*)&A1T[(size_t)(t*16 + lrow)*256 + k0 + lk];
            acc[t] = __builtin_amdgcn_mfma_f32_16x16x32_bf16(af, bf, acc[t], 0, 0, 0);
        }
    }
    #pragma unroll
    for (int t = 0; t < 8; t++) {
        int col = t*16 + lrow;
        float bv = a1b[col];
        #pragma unroll
        for (int j = 0; j < 4; j++) {
            int row = (l >> 4)*4 + j;
            float val = acc[t][j] + bv;
            val = val / (1.0f + __expf(-val));
            Hs[row][col] = f2bf(val);
        }
    }
    __syncthreads();

    f32x4 acc2[24];
    #pragma unroll
    for (int t = 0; t < 24; t++) acc2[t] = (f32x4){0.f,0.f,0.f,0.f};
    #pragma unroll
    for (int k0 = 0; k0 < 128; k0 += 32) {
        bf16x8 af = *(const bf16x8*)&Hs[lrow][k0 + lk];
        #pragma unroll
        for (int t = 0; t < 24; t++) {
            bf16x8 bf = *(const bf16x8*)&A2T[(size_t)(t*16 + lrow)*128 + k0 + lk];
            acc2[t] = __builtin_amdgcn_mfma_f32_16x16x32_bf16(af, bf, acc2[t], 0, 0, 0);
        }
    }

    // epilogue: a_vv = cols 0..127 (t 0..7), a_sv = t 8..15, a_ss = t 16..23
    #pragma unroll
    for (int t = 0; t < 8; t++) {
        int k = t*16 + lrow;
        float b_vv = a2b[k], b_sv = a2b[128 + k], b_ss = a2b[256 + k];
        #pragma unroll
        for (int j = 0; j < 4; j++) {
            int a = bm + (l >> 4)*4 + j;
            size_t base = (size_t)a*128 + k;
            float vv = acc2[t][j]      + b_vv;
            float sv = acc2[t + 8][j]  + b_sv;
            float ss = acc2[t + 16][j] + b_ss;
            float sn = S[base] + ss + sv * DOT[base];
            S[base] = sn; SBF[base] = f2bf(sn);
            #pragma unroll
            for (int c = 0; c < 3; c++) {
                size_t vb = (size_t)c*VPLANE + base;
                float nv = V[vb] + vv * UV[vb];
                V[vb] = nv; VBFA[vb] = f2bf(nv);
            }
        }
    }
}

// ---------------- fused readout: AOUT = silu(S@ow1+b1) . w2 + b2 ----------------
__global__ __launch_bounds__(64) void k_readout(
    const ushort* __restrict__ SBF, const ushort* __restrict__ OW1T,
    const float* __restrict__ b1, const float* __restrict__ w2,
    const float* __restrict__ b2v, float* __restrict__ AOUT)
{
    int l = threadIdx.x;
    int bm = blockIdx.x * 16;
    int lrow = l & 15, lk = (l >> 4) * 8;
    __shared__ float Hs[16][132];

    f32x4 acc[8];
    #pragma unroll
    for (int t = 0; t < 8; t++) acc[t] = (f32x4){0.f,0.f,0.f,0.f};
    #pragma unroll
    for (int k0 = 0; k0 < 128; k0 += 32) {
        bf16x8 af = *(const bf16x8*)&SBF[(size_t)(bm + lrow)*128 + k0 + lk];
        #pragma unroll
        for (int t = 0; t < 8; t++) {
            bf16x8 bf = *(const bf16x8*)&OW1T[(size_t)(t*16 + lrow)*128 + k0 + lk];
            acc[t] = __builtin_amdgcn_mfma_f32_16x16x32_bf16(af, bf, acc[t], 0, 0, 0);
        }
    }
    #pragma unroll
    for (int t = 0; t < 8; t++) {
        int col = t*16 + lrow;
        float bv = b1[col];
        #pragma unroll
        for (int j = 0; j < 4; j++) {
            int row = (l >> 4)*4 + j;
            float val = acc[t][j] + bv;
            Hs[row][col] = val / (1.0f + __expf(-val));
        }
    }
    __syncthreads();
    if (l < 16) {
        float s = b2v[0];
        #pragma unroll 8
        for (int k = 0; k < 128; k++) s += Hs[l][k] * w2[k];
        AOUT[bm + l] = s;
    }
}

// ---------------- per-molecule sum ----------------
__global__ void k_molsum(const float* __restrict__ AOUT, const int* __restrict__ mol,
                         float* __restrict__ out) {
    __shared__ float acc[N_MOL];
    int t = threadIdx.x;
    if (t < N_MOL) acc[t] = 0.f;
    __syncthreads();
    for (int i = blockIdx.x * 256 + t; i < N_ATOMS; i += 256 * 32)
        atomicAdd(&acc[mol[i]], AOUT[i]);
    __syncthreads();
    if (t < N_MOL) atomicAdd(&out[t], acc[t]);
}

extern "C" void kernel_launch(void* const* d_in, const int* in_sizes, int n_in,
                              void* d_out, int out_size, void* d_ws, size_t ws_size,
                              hipStream_t stream) {
    const int*   z      = (const int*)d_in[0];
    const float* pos    = (const float*)d_in[1];
    const int*   esrc   = (const int*)d_in[2];
    const int*   edst   = (const int*)d_in[3];
    const int*   mol    = (const int*)d_in[4];
    const float* embed  = (const float*)d_in[5];
    const float* msg_w1 = (const float*)d_in[6];
    const float* msg_b1 = (const float*)d_in[7];
    const float* msg_w2 = (const float*)d_in[8];
    const float* msg_b2 = (const float*)d_in[9];
    const float* rbf_w  = (const float*)d_in[10];
    const float* rbf_b  = (const float*)d_in[11];
    const float* upd_u  = (const float*)d_in[12];
    const float* upd_v  = (const float*)d_in[13];
    const float* upd_a1 = (const float*)d_in[14];
    const float* upd_a1b= (const float*)d_in[15];
    const float* upd_a2 = (const float*)d_in[16];
    const float* upd_a2b= (const float*)d_in[17];
    const float* out_w1 = (const float*)d_in[18];
    const float* out_b1 = (const float*)d_in[19];
    const float* out_w2 = (const float*)d_in[20];
    const float* out_b2 = (const float*)d_in[21];

    float* ws = (float*)d_ws;
    float* S      = ws; ws += 1048576;     // 8192*128 f32
    float* V      = ws; ws += 3145728;     // 3 planes [c][a][k]
    float* UV     = ws; ws += 3145728;     // 3 planes
    float* DOT    = ws; ws += 1048576;
    float* RBF    = ws; ws += 5242880;     // sorted
    float* UNITFC = ws; ws += 1048576;     // sorted
    float* AOUT   = ws; ws += 8192;
    ushort* PHIB  = (ushort*)ws; ws += 1572864;   // 8192*384
    ushort* VBFA  = (ushort*)ws; ws += 1572864;   // v bf16 planes (gather)
    ushort* VBFB  = (ushort*)ws; ws += 1572864;   // post-agg v bf16 planes (GEMM A)
    ushort* SBF   = (ushort*)ws; ws += 524288;
    ushort* VVNB  = (ushort*)ws; ws += 524288;
    ushort* WT    = (ushort*)ws; ws += 278528;
    int* CNT  = (int*)ws;
    int* OFF  = CNT + 8192;
    int* CUR  = OFF + 8193;
    int* POS  = CUR + 8192;
    int* SRCS = POS + N_EDGES;

    hipMemsetAsync(V, 0, 3145728 * sizeof(float), stream);
    hipMemsetAsync(VBFA, 0, 3145728 * sizeof(ushort), stream);
    hipMemsetAsync(CNT, 0, 8192 * sizeof(int), stream);

    k_wconv<<<2176, 256, 0, stream>>>(msg_w1, msg_w2, upd_u, upd_v, upd_a1, upd_a2, out_w1, WT);
    k_embed<<<4096, 256, 0, stream>>>(z, embed, S, SBF);
    k_hist<<<1024, 256, 0, stream>>>(edst, CNT);
    k_scan<<<1, 1024, 0, stream>>>(CNT, OFF, CUR);
    k_pos<<<1024, 256, 0, stream>>>(edst, CUR, POS);
    k_edges<<<1024, 256, 0, stream>>>(pos, esrc, edst, POS, RBF, UNITFC, SRCS);

    for (int l = 0; l < LLAYERS; l++) {
        const ushort* W1T = WT + l*16384;
        const ushort* W2T = WT + 49152  + l*49152;
        const ushort* UVT = WT + 196608 + l*32768;
        const ushort* A1T = WT + 294912 + l*32768;
        const ushort* A2T = WT + 393216 + l*49152;

        k_msg<<<512, 64, 0, stream>>>(SBF, W1T, msg_b1 + (size_t)l*128,
                                      W2T, msg_b2 + (size_t)l*384, PHIB);
        k_aggregate<<<8192, 192, 0, stream>>>(PHIB, VBFA, S, SBF, V, VBFB, RBF, UNITFC,
            SRCS, OFF, rbf_w + (size_t)l*20*384, rbf_b + (size_t)l*384);
        k_uvvv<<<512, 128, 0, stream>>>(VBFB, UVT, UV, VVNB, DOT);
        k_updmlp<<<512, 64, 0, stream>>>(SBF, VVNB, A1T, upd_a1b + (size_t)l*128,
            A2T, upd_a2b + (size_t)l*384, DOT, UV, S, SBF, V, VBFA);
    }

    k_readout<<<512, 64, 0, stream>>>(SBF, WT + 540672, out_b1, out_w2, out_b2, AOUT);
    hipMemsetAsync(d_out, 0, N_MOL * sizeof(float), stream);
    k_molsum<<<32, 256, 0, stream>>>(AOUT, mol, (float*)d_out);
}

// Round 9
// 619.214 us; speedup vs baseline: 1.2343x; 1.2343x over previous
//
#include <hip/hip_runtime.h>
#include <hip/hip_bf16.h>
#include <math.h>

#define N_ATOMS 8192
#define N_EDGES 262144
#define N_MOL   128
#define FDIM    128
#define RDIM    20
#define LLAYERS 3
#define CUTOFF  5.0f
#define EPSV    1e-8f
#define PI_F    3.14159265358979323846f

typedef __attribute__((ext_vector_type(8))) short bf16x8;
typedef __attribute__((ext_vector_type(4))) float f32x4;

#define VPLANE 1048576   // 8192*128 elements per component plane

__device__ __forceinline__ ushort f2bf(float x) {
    uint b = __float_as_uint(x);
    return (ushort)((b + 0x7fffu + ((b >> 16) & 1u)) >> 16);
}

// ---------------- weight convert+transpose (f32 KxN -> bf16 NxK) ----------------
__global__ void k_wconv(const float* __restrict__ w1, const float* __restrict__ w2,
                        const float* __restrict__ uu, const float* __restrict__ uvw,
                        const float* __restrict__ a1, const float* __restrict__ a2,
                        const float* __restrict__ ow1, ushort* __restrict__ WT) {
    int i = blockIdx.x * 256 + threadIdx.x;  // < 557056
    float v;
    if (i < 49152) {                          // W1T
        int idx = i; int l = idx >> 14; idx &= 16383;
        int n = idx >> 7, k = idx & 127;
        v = w1[l*16384 + k*128 + n];
    } else if (i < 196608) {                  // W2T
        int idx = i - 49152; int l = idx / 49152; idx -= l * 49152;
        int n = idx >> 7, k = idx & 127;
        v = w2[l*49152 + k*384 + n];
    } else if (i < 294912) {                  // UVT (u cols 0-127, v cols 128-255)
        int idx = i - 196608; int l = idx >> 15; idx &= 32767;
        int n = idx >> 7, k = idx & 127;
        v = (n < 128) ? uu[l*16384 + k*128 + n] : uvw[l*16384 + k*128 + (n-128)];
    } else if (i < 393216) {                  // A1T (128n x 256k)
        int idx = i - 294912; int l = idx >> 15; idx &= 32767;
        int n = idx >> 8, k = idx & 255;
        v = a1[l*32768 + k*128 + n];
    } else if (i < 540672) {                  // A2T
        int idx = i - 393216; int l = idx / 49152; idx -= l * 49152;
        int n = idx >> 7, k = idx & 127;
        v = a2[l*49152 + k*384 + n];
    } else {                                  // OW1T
        int idx = i - 540672;
        int n = idx >> 7, k = idx & 127;
        v = ow1[k*128 + n];
    }
    WT[i] = f2bf(v);
}

// ---------------- embed gather ----------------
__global__ void k_embed(const int* __restrict__ z, const float* __restrict__ embed,
                        float* __restrict__ S, ushort* __restrict__ SBF) {
    int i = blockIdx.x * 256 + threadIdx.x;
    int a = i >> 7, k = i & 127;
    float v = embed[(size_t)z[a] * FDIM + k];
    S[i] = v; SBF[i] = f2bf(v);
}

// ---------------- CSR build ----------------
__global__ void k_hist(const int* __restrict__ edst, int* __restrict__ CNT) {
    int e = blockIdx.x * 256 + threadIdx.x;
    if (e < N_EDGES) atomicAdd(&CNT[edst[e]], 1);
}

__global__ __launch_bounds__(1024) void k_scan(const int* __restrict__ CNT,
                                               int* __restrict__ OFF, int* __restrict__ CUR) {
    __shared__ int part[1024];
    int t = threadIdx.x;
    int loc[8];
    int run = 0;
    #pragma unroll
    for (int i = 0; i < 8; i++) { int c = CNT[t*8 + i]; loc[i] = run; run += c; }
    part[t] = run;
    __syncthreads();
    for (int off = 1; off < 1024; off <<= 1) {
        int v = 0;
        if (t >= off) v = part[t - off];
        __syncthreads();
        part[t] += v;
        __syncthreads();
    }
    int ebase = (t > 0) ? part[t-1] : 0;
    #pragma unroll
    for (int i = 0; i < 8; i++) { int o = ebase + loc[i]; OFF[t*8+i] = o; CUR[t*8+i] = o; }
    if (t == 1023) OFF[8192] = part[1023];
}

__global__ void k_pos(const int* __restrict__ edst, int* __restrict__ CUR,
                      int* __restrict__ POS) {
    int e = blockIdx.x * 256 + threadIdx.x;
    if (e < N_EDGES) POS[e] = atomicAdd(&CUR[edst[e]], 1);
}

// ---------------- edge geometry + rbf, CSR-sorted ----------------
__global__ void k_edges(const float* __restrict__ pos, const int* __restrict__ esrc,
                        const int* __restrict__ edst, const int* __restrict__ POS,
                        float* __restrict__ RBF, float* __restrict__ UNITFC,
                        int* __restrict__ SRCS) {
    int e = blockIdx.x * 256 + threadIdx.x;
    if (e >= N_EDGES) return;
    int s = esrc[e], d = edst[e];
    int p = POS[e];
    float rx = pos[d*3+0] - pos[s*3+0];
    float ry = pos[d*3+1] - pos[s*3+1];
    float rz = pos[d*3+2] - pos[s*3+2];
    float dd = sqrtf(rx*rx + ry*ry + rz*rz + EPSV);
    float inv = 1.0f / dd;
    float fc = (dd < CUTOFF) ? 0.5f * (cosf(dd * (PI_F / CUTOFF)) + 1.0f) : 0.0f;
    float4 u4; u4.x = rx*inv; u4.y = ry*inv; u4.z = rz*inv; u4.w = fc;
    *(float4*)&UNITFC[(size_t)p*4] = u4;
    SRCS[p] = s;
    float rb[RDIM];
    #pragma unroll
    for (int r = 0; r < RDIM; r++) {
        float freq = (float)(r + 1) * (PI_F / CUTOFF);
        rb[r] = sinf(dd * freq) * inv;
    }
    float4* out = (float4*)&RBF[(size_t)p * RDIM];
    #pragma unroll
    for (int q = 0; q < 5; q++) {
        float4 o; o.x = rb[q*4]; o.y = rb[q*4+1]; o.z = rb[q*4+2]; o.w = rb[q*4+3];
        out[q] = o;
    }
}

// ---------------- fused message MLP (4 waves): PHIB = (silu(S@w1+b1))@w2+b2 ----------------
__global__ __launch_bounds__(256) void k_msg(
    const ushort* __restrict__ SBF, const ushort* __restrict__ W1T, const float* __restrict__ b1,
    const ushort* __restrict__ W2T, const float* __restrict__ b2, ushort* __restrict__ PHIB)
{
    int tid = threadIdx.x;
    int w = tid >> 6, l = tid & 63;
    int bm = blockIdx.x * 16;
    int lrow = l & 15, lk = (l >> 4) * 8;
    __shared__ ushort Hs[16][136];

    f32x4 acc[2] = {{0.f,0.f,0.f,0.f},{0.f,0.f,0.f,0.f}};
    #pragma unroll
    for (int k0 = 0; k0 < 128; k0 += 32) {
        bf16x8 af = *(const bf16x8*)&SBF[(size_t)(bm + lrow)*128 + k0 + lk];
        #pragma unroll
        for (int t = 0; t < 2; t++) {
            int n = (2*w + t)*16 + lrow;
            bf16x8 bf = *(const bf16x8*)&W1T[(size_t)n*128 + k0 + lk];
            acc[t] = __builtin_amdgcn_mfma_f32_16x16x32_bf16(af, bf, acc[t], 0, 0, 0);
        }
    }
    #pragma unroll
    for (int t = 0; t < 2; t++) {
        int col = (2*w + t)*16 + lrow;
        float bv = b1[col];
        #pragma unroll
        for (int j = 0; j < 4; j++) {
            int row = (l >> 4)*4 + j;
            float val = acc[t][j] + bv;
            val = val / (1.0f + __expf(-val));
            Hs[row][col] = f2bf(val);
        }
    }
    __syncthreads();

    f32x4 acc2[6];
    #pragma unroll
    for (int t = 0; t < 6; t++) acc2[t] = (f32x4){0.f,0.f,0.f,0.f};
    #pragma unroll
    for (int k0 = 0; k0 < 128; k0 += 32) {
        bf16x8 af = *(const bf16x8*)&Hs[lrow][k0 + lk];
        #pragma unroll
        for (int t = 0; t < 6; t++) {
            int n = (6*w + t)*16 + lrow;
            bf16x8 bf = *(const bf16x8*)&W2T[(size_t)n*128 + k0 + lk];
            acc2[t] = __builtin_amdgcn_mfma_f32_16x16x32_bf16(af, bf, acc2[t], 0, 0, 0);
        }
    }
    #pragma unroll
    for (int t = 0; t < 6; t++) {
        int col = (6*w + t)*16 + lrow;
        float bv = b2[col];
        #pragma unroll
        for (int j = 0; j < 4; j++) {
            int row = bm + (l >> 4)*4 + j;
            PHIB[(size_t)row*384 + col] = f2bf(acc2[t][j] + bv);
        }
    }
}

// ---------------- edge aggregation (round-7 math, plane-major v) ----------------
__global__ __launch_bounds__(192) void k_aggregate(
    const ushort* __restrict__ PHIB, const ushort* __restrict__ VBFA,
    float* __restrict__ S, ushort* __restrict__ SBF,
    float* __restrict__ V, ushort* __restrict__ VBFB,
    const float* __restrict__ RBF, const float* __restrict__ UNITFC,
    const int* __restrict__ SRCS, const int* __restrict__ OFF,
    const float* __restrict__ rbfw, const float* __restrict__ rbfb)
{
    int a = blockIdx.x;
    int tid = threadIdx.x;
    int g = tid >> 6;          // wave role: 0=ds, 1=v*dvv, 2=unit*dvs
    int c0 = 2 * (tid & 63);   // channel pair within section

    float2 w[RDIM];
    const float* wc = rbfw + g*128 + c0;
    #pragma unroll
    for (int r = 0; r < RDIM; r++) { w[r].x = wc[r*384]; w[r].y = wc[r*384 + 1]; }
    float2 bb; bb.x = rbfb[g*128 + c0]; bb.y = rbfb[g*128 + c0 + 1];

    __shared__ int sSrc[64];
    __shared__ float4 sRBF[320];
    __shared__ float4 sUFC[64];
    __shared__ float avs[3][128];

    int beg = OFF[a], end = OFF[a + 1];
    float2 d; d.x = 0.f; d.y = 0.f;
    float2 A0, A1, A2v;
    A0.x=A0.y=A1.x=A1.y=A2v.x=A2v.y=0.f;

    for (int p0 = beg; p0 < end; p0 += 64) {
        int n = end - p0; if (n > 64) n = 64;
        __syncthreads();
        if (tid < n) sSrc[tid] = SRCS[p0 + tid];
        for (int i = tid; i < n; i += 192)
            sUFC[i] = *(const float4*)(UNITFC + (size_t)(p0 + i) * 4);
        {
            const float4* rsrc = (const float4*)(RBF + (size_t)p0 * RDIM);
            for (int i = tid; i < n*5; i += 192) sRBF[i] = rsrc[i];
        }
        __syncthreads();

        uint phA[4], u0A[4], u1A[4], u2A[4];
        uint phB[4], u0B[4], u1B[4], u2B[4];

        auto grpLoad = [&](int base, uint* ph, uint* u0, uint* u1, uint* u2) {
            #pragma unroll
            for (int j = 0; j < 4; j++) {
                int q = base + j;
                int src = sSrc[(q < n) ? q : 0];
                size_t pb = (size_t)src * 128;
                ph[j] = *(const uint*)&PHIB[(size_t)src*384 + g*128 + c0];
                if (g == 1) {
                    u0[j] = *(const uint*)&VBFA[pb + c0];
                    u1[j] = *(const uint*)&VBFA[pb + VPLANE + c0];
                    u2[j] = *(const uint*)&VBFA[pb + 2*VPLANE + c0];
                }
            }
        };
        grpLoad(0, phA, u0A, u1A, u2A);
        for (int q0 = 0; q0 < n; q0 += 4) {
            if (q0 + 4 < n) grpLoad(q0 + 4, phB, u0B, u1B, u2B);
            #pragma unroll
            for (int j = 0; j < 4; j++) {
                int q = q0 + j;
                if (q >= n) break;
                float4 r0 = sRBF[q*5+0], r1 = sRBF[q*5+1], r2 = sRBF[q*5+2],
                       r3 = sRBF[q*5+3], r4 = sRBF[q*5+4];
                float4 ufc = sUFC[q];
                float2 f = bb;
                f.x += r0.x*w[0].x;   f.y += r0.x*w[0].y;
                f.x += r0.y*w[1].x;   f.y += r0.y*w[1].y;
                f.x += r0.z*w[2].x;   f.y += r0.z*w[2].y;
                f.x += r0.w*w[3].x;   f.y += r0.w*w[3].y;
                f.x += r1.x*w[4].x;   f.y += r1.x*w[4].y;
                f.x += r1.y*w[5].x;   f.y += r1.y*w[5].y;
                f.x += r1.z*w[6].x;   f.y += r1.z*w[6].y;
                f.x += r1.w*w[7].x;   f.y += r1.w*w[7].y;
                f.x += r2.x*w[8].x;   f.y += r2.x*w[8].y;
                f.x += r2.y*w[9].x;   f.y += r2.y*w[9].y;
                f.x += r2.z*w[10].x;  f.y += r2.z*w[10].y;
                f.x += r2.w*w[11].x;  f.y += r2.w*w[11].y;
                f.x += r3.x*w[12].x;  f.y += r3.x*w[12].y;
                f.x += r3.y*w[13].x;  f.y += r3.y*w[13].y;
                f.x += r3.z*w[14].x;  f.y += r3.z*w[14].y;
                f.x += r3.w*w[15].x;  f.y += r3.w*w[15].y;
                f.x += r4.x*w[16].x;  f.y += r4.x*w[16].y;
                f.x += r4.y*w[17].x;  f.y += r4.y*w[17].y;
                f.x += r4.z*w[18].x;  f.y += r4.z*w[18].y;
                f.x += r4.w*w[19].x;  f.y += r4.w*w[19].y;
                uint up = phA[j];
                float m0 = __uint_as_float(up << 16)         * (f.x * ufc.w);
                float m1 = __uint_as_float(up & 0xffff0000u) * (f.y * ufc.w);
                if (g == 0) {
                    d.x += m0; d.y += m1;
                } else if (g == 1) {
                    A0.x  += __uint_as_float(u0A[j] << 16)         * m0;
                    A0.y  += __uint_as_float(u0A[j] & 0xffff0000u) * m1;
                    A1.x  += __uint_as_float(u1A[j] << 16)         * m0;
                    A1.y  += __uint_as_float(u1A[j] & 0xffff0000u) * m1;
                    A2v.x += __uint_as_float(u2A[j] << 16)         * m0;
                    A2v.y += __uint_as_float(u2A[j] & 0xffff0000u) * m1;
                } else {
                    A0.x  += ufc.x * m0; A0.y  += ufc.x * m1;
                    A1.x  += ufc.y * m0; A1.y  += ufc.y * m1;
                    A2v.x += ufc.z * m0; A2v.y += ufc.z * m1;
                }
            }
            #pragma unroll
            for (int j = 0; j < 4; j++) {
                phA[j] = phB[j]; u0A[j] = u0B[j]; u1A[j] = u1B[j]; u2A[j] = u2B[j];
            }
        }
    }

    if (g == 1) {
        avs[0][c0] = A0.x;  avs[0][c0+1] = A0.y;
        avs[1][c0] = A1.x;  avs[1][c0+1] = A1.y;
        avs[2][c0] = A2v.x; avs[2][c0+1] = A2v.y;
    }
    __syncthreads();
    if (g == 0) {
        size_t sb = (size_t)a*128 + c0;
        float2 s2 = *(float2*)&S[sb];
        s2.x += d.x; s2.y += d.y;
        *(float2*)&S[sb] = s2;
        SBF[sb] = f2bf(s2.x); SBF[sb+1] = f2bf(s2.y);
    } else if (g == 2) {
        float own0[3] = {A0.x, A1.x, A2v.x};
        float own1[3] = {A0.y, A1.y, A2v.y};
        #pragma unroll
        for (int c = 0; c < 3; c++) {
            size_t vb = (size_t)c*VPLANE + (size_t)a*128 + c0;
            float2 vi = *(const float2*)&V[vb];
            vi.x += avs[c][c0]     + own0[c];
            vi.y += avs[c][c0 + 1] + own1[c];
            *(float2*)&V[vb] = vi;
            VBFB[vb] = f2bf(vi.x); VBFB[vb+1] = f2bf(vi.y);
        }
    }
}

// ---------------- fused update: uv/vv GEMM + vvdot + a-MLP + s/v update ----------------
// 4 waves; wave w owns col-tiles {2w,2w+1} everywhere -> dot/uv stay in registers.
__global__ __launch_bounds__(256) void k_upd(
    const ushort* __restrict__ VBFB, const ushort* __restrict__ UVT,
    const ushort* __restrict__ SBF_in,
    const ushort* __restrict__ A1T, const float* __restrict__ a1b,
    const ushort* __restrict__ A2T, const float* __restrict__ a2b,
    float* __restrict__ S, ushort* __restrict__ SBF,
    float* __restrict__ V, ushort* __restrict__ VBFA)
{
    int tid = threadIdx.x;
    int w = tid >> 6, l = tid & 63;
    int bm = blockIdx.x * 16;
    int lrow = l & 15, lk = (l >> 4) * 8;
    __shared__ ushort sVVN[16][136];
    __shared__ ushort Hs[16][136];

    // ---- phase A: u = v@U, vv = v@Vw for col-tiles {2w, 2w+1} ----
    f32x4 au[3][2], av[3][2];
    #pragma unroll
    for (int c = 0; c < 3; c++)
        #pragma unroll
        for (int t = 0; t < 2; t++) {
            au[c][t] = (f32x4){0.f,0.f,0.f,0.f};
            av[c][t] = (f32x4){0.f,0.f,0.f,0.f};
        }
    #pragma unroll
    for (int k0 = 0; k0 < 128; k0 += 32) {
        bf16x8 af[3];
        #pragma unroll
        for (int c = 0; c < 3; c++)
            af[c] = *(const bf16x8*)&VBFB[(size_t)c*VPLANE + (size_t)(bm + lrow)*128 + k0 + lk];
        #pragma unroll
        for (int t = 0; t < 2; t++) {
            int nu = (2*w + t)*16 + lrow;
            bf16x8 bu = *(const bf16x8*)&UVT[(size_t)nu*128 + k0 + lk];
            bf16x8 bv = *(const bf16x8*)&UVT[(size_t)(nu + 128)*128 + k0 + lk];
            #pragma unroll
            for (int c = 0; c < 3; c++) {
                au[c][t] = __builtin_amdgcn_mfma_f32_16x16x32_bf16(af[c], bu, au[c][t], 0, 0, 0);
                av[c][t] = __builtin_amdgcn_mfma_f32_16x16x32_bf16(af[c], bv, av[c][t], 0, 0, 0);
            }
        }
    }
    float dotr[2][4], uvr[3][2][4];
    #pragma unroll
    for (int t = 0; t < 2; t++) {
        int k = (2*w + t)*16 + lrow;
        #pragma unroll
        for (int j = 0; j < 4; j++) {
            int row = (l >> 4)*4 + j;
            float u0 = au[0][t][j], u1 = au[1][t][j], u2 = au[2][t][j];
            float v0 = av[0][t][j], v1 = av[1][t][j], v2 = av[2][t][j];
            uvr[0][t][j] = u0; uvr[1][t][j] = u1; uvr[2][t][j] = u2;
            dotr[t][j] = u0*v0 + u1*v1 + u2*v2;
            sVVN[row][k] = f2bf(sqrtf(v0*v0 + v1*v1 + v2*v2 + EPSV));
        }
    }
    __syncthreads();

    // ---- phase B: h = silu([S|VVN]@a1 + b1) for col-tiles {2w, 2w+1} ----
    f32x4 acc[2] = {{0.f,0.f,0.f,0.f},{0.f,0.f,0.f,0.f}};
    #pragma unroll
    for (int k0 = 0; k0 < 256; k0 += 32) {
        bf16x8 af;
        if (k0 < 128) af = *(const bf16x8*)&SBF_in[(size_t)(bm + lrow)*128 + k0 + lk];
        else          af = *(const bf16x8*)&sVVN[lrow][k0 + lk - 128];
        #pragma unroll
        for (int t = 0; t < 2; t++) {
            int n = (2*w + t)*16 + lrow;
            bf16x8 bf = *(const bf16x8*)&A1T[(size_t)n*256 + k0 + lk];
            acc[t] = __builtin_amdgcn_mfma_f32_16x16x32_bf16(af, bf, acc[t], 0, 0, 0);
        }
    }
    #pragma unroll
    for (int t = 0; t < 2; t++) {
        int col = (2*w + t)*16 + lrow;
        float bv = a1b[col];
        #pragma unroll
        for (int j = 0; j < 4; j++) {
            int row = (l >> 4)*4 + j;
            float val = acc[t][j] + bv;
            val = val / (1.0f + __expf(-val));
            Hs[row][col] = f2bf(val);
        }
    }
    __syncthreads();

    // ---- phase C: a = h@a2 + b2; tiles {2w,2w+1}(vv), +8(sv), +16(ss) ----
    f32x4 c_vv[2], c_sv[2], c_ss[2];
    #pragma unroll
    for (int t = 0; t < 2; t++) {
        c_vv[t] = (f32x4){0.f,0.f,0.f,0.f};
        c_sv[t] = (f32x4){0.f,0.f,0.f,0.f};
        c_ss[t] = (f32x4){0.f,0.f,0.f,0.f};
    }
    #pragma unroll
    for (int k0 = 0; k0 < 128; k0 += 32) {
        bf16x8 af = *(const bf16x8*)&Hs[lrow][k0 + lk];
        #pragma unroll
        for (int t = 0; t < 2; t++) {
            int n0 = (2*w + t)*16 + lrow;
            bf16x8 b0 = *(const bf16x8*)&A2T[(size_t)n0*128 + k0 + lk];
            bf16x8 b1 = *(const bf16x8*)&A2T[(size_t)(n0 + 128)*128 + k0 + lk];
            bf16x8 b2 = *(const bf16x8*)&A2T[(size_t)(n0 + 256)*128 + k0 + lk];
            c_vv[t] = __builtin_amdgcn_mfma_f32_16x16x32_bf16(af, b0, c_vv[t], 0, 0, 0);
            c_sv[t] = __builtin_amdgcn_mfma_f32_16x16x32_bf16(af, b1, c_sv[t], 0, 0, 0);
            c_ss[t] = __builtin_amdgcn_mfma_f32_16x16x32_bf16(af, b2, c_ss[t], 0, 0, 0);
        }
    }
    #pragma unroll
    for (int t = 0; t < 2; t++) {
        int k = (2*w + t)*16 + lrow;
        float b_vv = a2b[k], b_sv = a2b[128 + k], b_ss = a2b[256 + k];
        #pragma unroll
        for (int j = 0; j < 4; j++) {
            int a = bm + (l >> 4)*4 + j;
            size_t base = (size_t)a*128 + k;
            float vv = c_vv[t][j] + b_vv;
            float sv = c_sv[t][j] + b_sv;
            float ss = c_ss[t][j] + b_ss;
            float sn = S[base] + ss + sv * dotr[t][j];
            S[base] = sn; SBF[base] = f2bf(sn);
            #pragma unroll
            for (int c = 0; c < 3; c++) {
                size_t vb = (size_t)c*VPLANE + base;
                float nv = V[vb] + vv * uvr[c][t][j];
                V[vb] = nv; VBFA[vb] = f2bf(nv);
            }
        }
    }
}

// ---------------- fused readout: AOUT = silu(S@ow1+b1) . w2 + b2 ----------------
__global__ __launch_bounds__(64) void k_readout(
    const ushort* __restrict__ SBF, const ushort* __restrict__ OW1T,
    const float* __restrict__ b1, const float* __restrict__ w2,
    const float* __restrict__ b2v, float* __restrict__ AOUT)
{
    int l = threadIdx.x;
    int bm = blockIdx.x * 16;
    int lrow = l & 15, lk = (l >> 4) * 8;
    __shared__ float Hs[16][132];

    f32x4 acc[8];
    #pragma unroll
    for (int t = 0; t < 8; t++) acc[t] = (f32x4){0.f,0.f,0.f,0.f};
    #pragma unroll
    for (int k0 = 0; k0 < 128; k0 += 32) {
        bf16x8 af = *(const bf16x8*)&SBF[(size_t)(bm + lrow)*128 + k0 + lk];
        #pragma unroll
        for (int t = 0; t < 8; t++) {
            bf16x8 bf = *(const bf16x8*)&OW1T[(size_t)(t*16 + lrow)*128 + k0 + lk];
            acc[t] = __builtin_amdgcn_mfma_f32_16x16x32_bf16(af, bf, acc[t], 0, 0, 0);
        }
    }
    #pragma unroll
    for (int t = 0; t < 8; t++) {
        int col = t*16 + lrow;
        float bv = b1[col];
        #pragma unroll
        for (int j = 0; j < 4; j++) {
            int row = (l >> 4)*4 + j;
            float val = acc[t][j] + bv;
            Hs[row][col] = val / (1.0f + __expf(-val));
        }
    }
    __syncthreads();
    if (l < 16) {
        float s = b2v[0];
        #pragma unroll 8
        for (int k = 0; k < 128; k++) s += Hs[l][k] * w2[k];
        AOUT[bm + l] = s;
    }
}

// ---------------- per-molecule sum ----------------
__global__ void k_molsum(const float* __restrict__ AOUT, const int* __restrict__ mol,
                         float* __restrict__ out) {
    __shared__ float acc[N_MOL];
    int t = threadIdx.x;
    if (t < N_MOL) acc[t] = 0.f;
    __syncthreads();
    for (int i = blockIdx.x * 256 + t; i < N_ATOMS; i += 256 * 32)
        atomicAdd(&acc[mol[i]], AOUT[i]);
    __syncthreads();
    if (t < N_MOL) atomicAdd(&out[t], acc[t]);
}

extern "C" void kernel_launch(void* const* d_in, const int* in_sizes, int n_in,
                              void* d_out, int out_size, void* d_ws, size_t ws_size,
                              hipStream_t stream) {
    const int*   z      = (const int*)d_in[0];
    const float* pos    = (const float*)d_in[1];
    const int*   esrc   = (const int*)d_in[2];
    const int*   edst   = (const int*)d_in[3];
    const int*   mol    = (const int*)d_in[4];
    const float* embed  = (const float*)d_in[5];
    const float* msg_w1 = (const float*)d_in[6];
    const float* msg_b1 = (const float*)d_in[7];
    const float* msg_w2 = (const float*)d_in[8];
    const float* msg_b2 = (const float*)d_in[9];
    const float* rbf_w  = (const float*)d_in[10];
    const float* rbf_b  = (const float*)d_in[11];
    const float* upd_u  = (const float*)d_in[12];
    const float* upd_v  = (const float*)d_in[13];
    const float* upd_a1 = (const float*)d_in[14];
    const float* upd_a1b= (const float*)d_in[15];
    const float* upd_a2 = (const float*)d_in[16];
    const float* upd_a2b= (const float*)d_in[17];
    const float* out_w1 = (const float*)d_in[18];
    const float* out_b1 = (const float*)d_in[19];
    const float* out_w2 = (const float*)d_in[20];
    const float* out_b2 = (const float*)d_in[21];

    float* ws = (float*)d_ws;
    float* S      = ws; ws += 1048576;     // 8192*128 f32
    float* V      = ws; ws += 3145728;     // 3 planes [c][a][k]
    float* RBF    = ws; ws += 5242880;     // sorted
    float* UNITFC = ws; ws += 1048576;     // sorted
    float* AOUT   = ws; ws += 8192;
    ushort* PHIB  = (ushort*)ws; ws += 1572864;   // 8192*384
    ushort* VBFA  = (ushort*)ws; ws += 1572864;   // v bf16 planes (gather)
    ushort* VBFB  = (ushort*)ws; ws += 1572864;   // post-agg v bf16 planes (GEMM A)
    ushort* SBF   = (ushort*)ws; ws += 524288;
    ushort* WT    = (ushort*)ws; ws += 278528;
    int* CNT  = (int*)ws;
    int* OFF  = CNT + 8192;
    int* CUR  = OFF + 8193;
    int* POS  = CUR + 8192;
    int* SRCS = POS + N_EDGES;

    hipMemsetAsync(V, 0, 3145728 * sizeof(float), stream);
    hipMemsetAsync(VBFA, 0, 3145728 * sizeof(ushort), stream);
    hipMemsetAsync(CNT, 0, 8192 * sizeof(int), stream);

    k_wconv<<<2176, 256, 0, stream>>>(msg_w1, msg_w2, upd_u, upd_v, upd_a1, upd_a2, out_w1, WT);
    k_embed<<<4096, 256, 0, stream>>>(z, embed, S, SBF);
    k_hist<<<1024, 256, 0, stream>>>(edst, CNT);
    k_scan<<<1, 1024, 0, stream>>>(CNT, OFF, CUR);
    k_pos<<<1024, 256, 0, stream>>>(edst, CUR, POS);
    k_edges<<<1024, 256, 0, stream>>>(pos, esrc, edst, POS, RBF, UNITFC, SRCS);

    for (int l = 0; l < LLAYERS; l++) {
        const ushort* W1T = WT + l*16384;
        const ushort* W2T = WT + 49152  + l*49152;
        const ushort* UVT = WT + 196608 + l*32768;
        const ushort* A1T = WT + 294912 + l*32768;
        const ushort* A2T = WT + 393216 + l*49152;

        k_msg<<<512, 256, 0, stream>>>(SBF, W1T, msg_b1 + (size_t)l*128,
                                       W2T, msg_b2 + (size_t)l*384, PHIB);
        k_aggregate<<<8192, 192, 0, stream>>>(PHIB, VBFA, S, SBF, V, VBFB, RBF, UNITFC,
            SRCS, OFF, rbf_w + (size_t)l*20*384, rbf_b + (size_t)l*384);
        k_upd<<<512, 256, 0, stream>>>(VBFB, UVT, SBF, A1T, upd_a1b + (size_t)l*128,
            A2T, upd_a2b + (size_t)l*384, S, SBF, V, VBFA);
    }

    k_readout<<<512, 64, 0, stream>>>(SBF, WT + 540672, out_b1, out_w2, out_b2, AOUT);
    hipMemsetAsync(d_out, 0, N_MOL * sizeof(float), stream);
    k_molsum<<<32, 256, 0, stream>>>(AOUT, mol, (float*)d_out);
}